// Round 6
// baseline (1902.200 us; speedup 1.0000x reference)
//
#include <hip/hip_runtime.h>
#include <hip/hip_bf16.h>
#include <hip/hip_fp16.h>

#define BCONST 128
#define LLEN   1024
#define INDIM  64
#define HDIM   256
#define DI     512           // D_INNER
#define NST    16
#define NCLS   12
#define MROWS  (BCONST*LLEN) // 131072

__device__ __forceinline__ float sigmoidf_(float x) {
    return __fdividef(1.0f, 1.0f + __expf(-x));
}

// ---------------------------------------------------------------------------
// fold_k: Wcomb = W_proj_in(64x256) @ W_in(256x1024); bcomb = b_proj_in @ W_in
// ---------------------------------------------------------------------------
__global__ __launch_bounds__(256) void fold_k(
    const float* __restrict__ Wp, const float* __restrict__ bp,
    const float* __restrict__ Win, float* __restrict__ Wcomb,
    float* __restrict__ bcomb)
{
    const int k = blockIdx.x >> 2;
    const int n = (blockIdx.x & 3) * 256 + threadIdx.x;
    float acc = 0.f;
    for (int j = 0; j < 256; j++)
        acc = fmaf(Wp[k * 256 + j], Win[(size_t)j * 1024 + n], acc);
    Wcomb[(size_t)k * 1024 + n] = acc;
    if (k == 0) {
        float bacc = 0.f;
        for (int j = 0; j < 256; j++)
            bacc = fmaf(bp[j], Win[(size_t)j * 1024 + n], bacc);
        bcomb[n] = bacc;
    }
}

// ---------------------------------------------------------------------------
// convgemm_k (BM=64, ~35KB LDS -> 4 blocks/CU):
//   xm path (kt<512):  raw xm GEMV -> conv -> silu -> As; GEMM into xdbl;
//                      EMIT: store As as fp16 xms.
//   z path (kt>=512, EMIT only): z GEMV -> silu -> fp16 zss store.
// ---------------------------------------------------------------------------
template<int EMIT>
__global__ __launch_bounds__(256) void convgemm_k(
    const float* __restrict__ x, const float* __restrict__ Wcomb,
    const float* __restrict__ bcomb, const float* __restrict__ Wx,
    const float* __restrict__ cw, const float* __restrict__ cb,
    float* __restrict__ xdbl, __half* __restrict__ xms,
    __half* __restrict__ zss)
{
    __shared__ float xrows[67][68];   // tokens [gm0-3, gm0+64)
    __shared__ float rawL[67][17];
    __shared__ float As[16][68];      // [kd][row]
    __shared__ float Bs[16][48];
    __shared__ float wtile[64][16];
    __shared__ float cwt[16][4];
    __shared__ float cbt[16];
    __shared__ float bct[16];

    const int tid  = threadIdx.x;
    const int tni  = tid & 15;
    const int tmi  = tid >> 4;
    const int mykd = tid & 15;
    const int gm0  = blockIdx.x * 64;
    const bool bstart = ((gm0 & (LLEN - 1)) == 0);

    for (int q = tid; q < 67 * 16; q += 256) {
        int i = q >> 4, jq = (q & 15) * 4;
        int tok = gm0 - 3 + i;
        float4 v = make_float4(0.f, 0.f, 0.f, 0.f);
        if (tok >= 0)
            v = *reinterpret_cast<const float4*>(&x[(size_t)tok * INDIM + jq]);
        *reinterpret_cast<float4*>(&xrows[i][jq]) = v;
    }

    float acc[4][3];
#pragma unroll
    for (int i = 0; i < 4; i++)
#pragma unroll
        for (int j = 0; j < 3; j++) acc[i][j] = 0.f;

    float wcol[64];
    const int ktEnd = EMIT ? 1024 : 512;

    for (int kt = 0; kt < ktEnd; kt += 16) {
        const bool isZ = (kt >= 512);
        __syncthreads();
        for (int q = tid; q < 64 * 16; q += 256) {
            int j = q >> 4, kd = q & 15;
            wtile[j][kd] = Wcomb[(size_t)j * 1024 + kt + kd];
        }
        if (!isZ) {
            for (int q = tid; q < 768; q += 256) {
                int kr = q / 48, nc = q - kr * 48;
                Bs[kr][nc] = Wx[(size_t)(kt + kr) * 48 + nc];
            }
            if (tid < 16) { cbt[tid] = cb[kt + tid]; bct[tid] = bcomb[kt + tid]; }
            if (tid < 64) cwt[tid >> 2][tid & 3] = cw[(kt + (tid >> 2)) * 4 + (tid & 3)];
        } else {
            if (tid < 16) bct[tid] = bcomb[kt + tid];
        }
        __syncthreads();

#pragma unroll
        for (int j = 0; j < 64; j++) wcol[j] = wtile[j][mykd];

        if (!isZ) {
            for (int q = tid; q < 67 * 16; q += 256) {
                int ro = q >> 4;
                float r = 0.f;
                if (!(bstart && ro < 3)) {
                    r = bct[mykd];
#pragma unroll
                    for (int j4 = 0; j4 < 16; j4++) {
                        float4 xv = *reinterpret_cast<const float4*>(&xrows[ro][j4 * 4]);
                        r = fmaf(xv.x, wcol[j4 * 4 + 0], r);
                        r = fmaf(xv.y, wcol[j4 * 4 + 1], r);
                        r = fmaf(xv.z, wcol[j4 * 4 + 2], r);
                        r = fmaf(xv.w, wcol[j4 * 4 + 3], r);
                    }
                }
                rawL[ro][mykd] = r;
            }
            __syncthreads();

            for (int q = tid; q < 64 * 16; q += 256) {
                int row = q >> 4;
                float v = cbt[mykd];
                v = fmaf(rawL[row + 0][mykd], cwt[mykd][0], v);
                v = fmaf(rawL[row + 1][mykd], cwt[mykd][1], v);
                v = fmaf(rawL[row + 2][mykd], cwt[mykd][2], v);
                v = fmaf(rawL[row + 3][mykd], cwt[mykd][3], v);
                float s = v * sigmoidf_(v);
                As[mykd][row] = s;
                if (EMIT)
                    xms[(size_t)(gm0 + row) * DI + kt + mykd] = __float2half(s);
            }
            __syncthreads();

#pragma unroll
            for (int kk = 0; kk < 16; kk++) {
                float4 a = *reinterpret_cast<const float4*>(&As[kk][tmi * 4]);
                float av[4] = {a.x, a.y, a.z, a.w};
                float b0 = Bs[kk][tni * 3 + 0];
                float b1 = Bs[kk][tni * 3 + 1];
                float b2 = Bs[kk][tni * 3 + 2];
#pragma unroll
                for (int i = 0; i < 4; i++) {
                    acc[i][0] = fmaf(av[i], b0, acc[i][0]);
                    acc[i][1] = fmaf(av[i], b1, acc[i][1]);
                    acc[i][2] = fmaf(av[i], b2, acc[i][2]);
                }
            }
        } else {
            // z path: rows 3..66 = tokens gm0..gm0+63
            for (int q = tid; q < 64 * 16; q += 256) {
                int ro = 3 + (q >> 4);
                float r = bct[mykd];
#pragma unroll
                for (int j4 = 0; j4 < 16; j4++) {
                    float4 xv = *reinterpret_cast<const float4*>(&xrows[ro][j4 * 4]);
                    r = fmaf(xv.x, wcol[j4 * 4 + 0], r);
                    r = fmaf(xv.y, wcol[j4 * 4 + 1], r);
                    r = fmaf(xv.z, wcol[j4 * 4 + 2], r);
                    r = fmaf(xv.w, wcol[j4 * 4 + 3], r);
                }
                float s = r * sigmoidf_(r);
                zss[(size_t)(gm0 + ro - 3) * DI + (kt - 512) + mykd] =
                    __float2half(s);
            }
        }
    }

#pragma unroll
    for (int i = 0; i < 4; i++) {
        const int gm = gm0 + tmi * 4 + i;
#pragma unroll
        for (int j = 0; j < 3; j++)
            xdbl[(size_t)gm * 48 + tni * 3 + j] = acc[i][j];
    }
}

// ---------------------------------------------------------------------------
// scanA2_k (Path A): chunked scan reading precomputed fp16 xms/zss.
// Register arrays = 80 floats -> no scratch spill; 4 waves/SIMD target.
// ---------------------------------------------------------------------------
__global__ __launch_bounds__(256, 4) void scanA2_k(
    const __half* __restrict__ xms, const __half* __restrict__ zss,
    const float* __restrict__ xdbl, const float* __restrict__ Wdt,
    const float* __restrict__ bdt_g, const float* __restrict__ Alog,
    const float* __restrict__ Dp_g, int Lc,
    float* __restrict__ Pprod, float* __restrict__ Hloc,
    float* __restrict__ Kcoef, float* __restrict__ AccLoc)
{
    const int tid = threadIdx.x;
    const int d   = blockIdx.x * 256 + tid;
    const int c   = blockIdx.y;
    const int P   = gridDim.y;
    const int b   = blockIdx.z;
    const int l0  = c * Lc;

    float wdt[16], Av[16], h[16], p[16], K[16];
#pragma unroll
    for (int r = 0; r < 16; r++) wdt[r] = Wdt[r * DI + d];
#pragma unroll
    for (int n = 0; n < 16; n++) Av[n] = -__expf(Alog[d * 16 + n]);
#pragma unroll
    for (int n = 0; n < 16; n++) { h[n] = 0.f; p[n] = 1.f; K[n] = 0.f; }

    const float bdt = bdt_g[d], Dpv = Dp_g[d];

    const __half* xmp = xms + ((size_t)b * LLEN + l0) * DI + d;
    const __half* zsp = zss + ((size_t)b * LLEN + l0) * DI + d;
    const float*  rw0 = xdbl + ((size_t)b * LLEN + l0) * 48;

    float acc = 0.f;

    for (int t = 0; t < Lc; t++) {
        float xv_ = __half2float(xmp[(size_t)t * DI]);
        float zs  = __half2float(zsp[(size_t)t * DI]);
        const float* rw = rw0 + (size_t)t * 48;   // wave-uniform

        float dtp = bdt;
#pragma unroll
        for (int r4 = 0; r4 < 4; r4++) {
            float4 rv = *reinterpret_cast<const float4*>(rw + r4 * 4);
            dtp = fmaf(rv.x, wdt[r4 * 4 + 0], dtp);
            dtp = fmaf(rv.y, wdt[r4 * 4 + 1], dtp);
            dtp = fmaf(rv.z, wdt[r4 * 4 + 2], dtp);
            dtp = fmaf(rv.w, wdt[r4 * 4 + 3], dtp);
        }
        float dt = (dtp > 15.f) ? dtp : __logf(1.f + __expf(dtp));
        float dtx = dt * xv_;
        float y = 0.f;
#pragma unroll
        for (int n4 = 0; n4 < 4; n4++) {
            float4 Bv = *reinterpret_cast<const float4*>(rw + 16 + n4 * 4);
            float4 Cv = *reinterpret_cast<const float4*>(rw + 32 + n4 * 4);
            float Ba[4] = {Bv.x, Bv.y, Bv.z, Bv.w};
            float Ca[4] = {Cv.x, Cv.y, Cv.z, Cv.w};
#pragma unroll
            for (int q = 0; q < 4; q++) {
                int n = n4 * 4 + q;
                float e = __expf(dt * Av[n]);
                h[n] = fmaf(e, h[n], dtx * Ba[q]);
                p[n] *= e;
                y = fmaf(h[n], Ca[q], y);
                K[n] = fmaf(p[n], Ca[q] * zs, K[n]);
            }
        }
        acc = fmaf(y + xv_ * Dpv, zs, acc);
    }

    const size_t nbase = ((size_t)(b * P + c) * 16) * DI + d;
#pragma unroll
    for (int n = 0; n < 16; n++) {
        Pprod[nbase + (size_t)n * DI] = p[n];
        Hloc [nbase + (size_t)n * DI] = h[n];
        Kcoef[nbase + (size_t)n * DI] = K[n];
    }
    AccLoc[(size_t)(b * P + c) * DI + d] = acc;
}

// ---------------------------------------------------------------------------
// scanA_k (Path B fallback, = R5): recomputes xm/z per step (spills, slower).
// ---------------------------------------------------------------------------
__global__ __launch_bounds__(256) void scanA_k(
    const float* __restrict__ x, const float* __restrict__ Wcomb,
    const float* __restrict__ bcomb, const float* __restrict__ xdbl,
    const float* __restrict__ Wdt, const float* __restrict__ bdt_g,
    const float* __restrict__ Alog, const float* __restrict__ Dp_g,
    const float* __restrict__ cw, const float* __restrict__ cb, int Lc,
    float* __restrict__ Pprod, float* __restrict__ Hloc,
    float* __restrict__ Kcoef, float* __restrict__ AccLoc)
{
    const int tid = threadIdx.x;
    const int d   = blockIdx.x * 256 + tid;
    const int c   = blockIdx.y;
    const int P   = gridDim.y;
    const int b   = blockIdx.z;
    const int l0  = c * Lc;

    float wxm[64], wz[64], wdt[16], Av[16], h[16], p[16], K[16];
#pragma unroll
    for (int j = 0; j < 64; j++) wxm[j] = Wcomb[(size_t)j * 1024 + d];
#pragma unroll
    for (int j = 0; j < 64; j++) wz[j] = Wcomb[(size_t)j * 1024 + 512 + d];
#pragma unroll
    for (int r = 0; r < 16; r++) wdt[r] = Wdt[r * DI + d];
#pragma unroll
    for (int n = 0; n < 16; n++) Av[n] = -__expf(Alog[d * 16 + n]);
#pragma unroll
    for (int n = 0; n < 16; n++) { h[n] = 0.f; p[n] = 1.f; K[n] = 0.f; }

    const float bxm = bcomb[d], bz = bcomb[512 + d];
    const float bdt = bdt_g[d], Dpv = Dp_g[d], cbv = cb[d];
    const float4 cwv = *reinterpret_cast<const float4*>(&cw[d * 4]);

    const float* xb  = x + (size_t)b * LLEN * INDIM;
    const float* xdb = xdbl + (size_t)b * LLEN * 48;

    float wbuf[3];
#pragma unroll
    for (int ii = 0; ii < 3; ii++) {
        int l = l0 - 3 + ii;
        float v = 0.f;
        if (l >= 0) {
            v = bxm;
            const float* xr = xb + (size_t)l * INDIM;
#pragma unroll
            for (int j4 = 0; j4 < 16; j4++) {
                float4 xv = *reinterpret_cast<const float4*>(xr + j4 * 4);
                v = fmaf(xv.x, wxm[j4 * 4 + 0], v);
                v = fmaf(xv.y, wxm[j4 * 4 + 1], v);
                v = fmaf(xv.z, wxm[j4 * 4 + 2], v);
                v = fmaf(xv.w, wxm[j4 * 4 + 3], v);
            }
        }
        wbuf[ii] = v;
    }
    float w0 = wbuf[0], w1 = wbuf[1], w2 = wbuf[2], acc = 0.f;

    for (int t = 0; t < Lc; t++) {
        const int l = l0 + t;
        const float* xr = xb + (size_t)l * INDIM;
        const float* rw = xdb + (size_t)l * 48;

        float xm_pre = bxm, z_pre = bz;
#pragma unroll
        for (int j4 = 0; j4 < 16; j4++) {
            float4 xv = *reinterpret_cast<const float4*>(xr + j4 * 4);
            xm_pre = fmaf(xv.x, wxm[j4 * 4 + 0], xm_pre);
            xm_pre = fmaf(xv.y, wxm[j4 * 4 + 1], xm_pre);
            xm_pre = fmaf(xv.z, wxm[j4 * 4 + 2], xm_pre);
            xm_pre = fmaf(xv.w, wxm[j4 * 4 + 3], xm_pre);
            z_pre  = fmaf(xv.x, wz[j4 * 4 + 0], z_pre);
            z_pre  = fmaf(xv.y, wz[j4 * 4 + 1], z_pre);
            z_pre  = fmaf(xv.z, wz[j4 * 4 + 2], z_pre);
            z_pre  = fmaf(xv.w, wz[j4 * 4 + 3], z_pre);
        }
        float zs = z_pre * sigmoidf_(z_pre);
        float conv = fmaf(w0, cwv.x, fmaf(w1, cwv.y,
                     fmaf(w2, cwv.z, fmaf(xm_pre, cwv.w, cbv))));
        w0 = w1; w1 = w2; w2 = xm_pre;
        float xv_ = conv * sigmoidf_(conv);

        float dtp = bdt;
#pragma unroll
        for (int r4 = 0; r4 < 4; r4++) {
            float4 rv = *reinterpret_cast<const float4*>(rw + r4 * 4);
            dtp = fmaf(rv.x, wdt[r4 * 4 + 0], dtp);
            dtp = fmaf(rv.y, wdt[r4 * 4 + 1], dtp);
            dtp = fmaf(rv.z, wdt[r4 * 4 + 2], dtp);
            dtp = fmaf(rv.w, wdt[r4 * 4 + 3], dtp);
        }
        float dt = (dtp > 15.f) ? dtp : __logf(1.f + __expf(dtp));
        float dtx = dt * xv_;
        float y = 0.f;
#pragma unroll
        for (int n4 = 0; n4 < 4; n4++) {
            float4 Bv = *reinterpret_cast<const float4*>(rw + 16 + n4 * 4);
            float4 Cv = *reinterpret_cast<const float4*>(rw + 32 + n4 * 4);
            float Ba[4] = {Bv.x, Bv.y, Bv.z, Bv.w};
            float Ca[4] = {Cv.x, Cv.y, Cv.z, Cv.w};
#pragma unroll
            for (int q = 0; q < 4; q++) {
                int n = n4 * 4 + q;
                float e = __expf(dt * Av[n]);
                h[n] = fmaf(e, h[n], dtx * Ba[q]);
                p[n] *= e;
                y = fmaf(h[n], Ca[q], y);
                K[n] = fmaf(p[n], Ca[q] * zs, K[n]);
            }
        }
        acc = fmaf(y + xv_ * Dpv, zs, acc);
    }

    const size_t nbase = ((size_t)(b * P + c) * 16) * DI + d;
#pragma unroll
    for (int n = 0; n < 16; n++) {
        Pprod[nbase + (size_t)n * DI] = p[n];
        Hloc [nbase + (size_t)n * DI] = h[n];
        Kcoef[nbase + (size_t)n * DI] = K[n];
    }
    AccLoc[(size_t)(b * P + c) * DI + d] = acc;
}

// ---------------------------------------------------------------------------
// scanB_k: chain the P chunks per (b,d) and emit pooled.
// ---------------------------------------------------------------------------
__global__ __launch_bounds__(256) void scanB_k(
    const float* __restrict__ Pprod, const float* __restrict__ Hloc,
    const float* __restrict__ Kcoef, const float* __restrict__ AccLoc,
    int P, float* __restrict__ pooled)
{
    const int tid = threadIdx.x;
    const int d   = blockIdx.x * 256 + tid;
    const int b   = blockIdx.y;
    float h[16];
#pragma unroll
    for (int n = 0; n < 16; n++) h[n] = 0.f;
    float acc = 0.f;
    for (int c = 0; c < P; c++) {
        const size_t nbase = ((size_t)(b * P + c) * 16) * DI + d;
        acc += AccLoc[(size_t)(b * P + c) * DI + d];
#pragma unroll
        for (int n = 0; n < 16; n++)
            acc = fmaf(Kcoef[nbase + (size_t)n * DI], h[n], acc);
#pragma unroll
        for (int n = 0; n < 16; n++)
            h[n] = fmaf(Pprod[nbase + (size_t)n * DI], h[n],
                        Hloc[nbase + (size_t)n * DI]);
    }
    pooled[(size_t)b * DI + d] = acc * (1.0f / LLEN);
}

// ---------------------------------------------------------------------------
__global__ __launch_bounds__(256) void cls_k(
    const float* __restrict__ pooled, const float* __restrict__ Wout,
    const float* __restrict__ Wc1, const float* __restrict__ bc1,
    const float* __restrict__ Wc2, const float* __restrict__ bc2,
    float* __restrict__ out)
{
    __shared__ float sp[512];
    __shared__ float s1[256];
    __shared__ float s2[128];
    const int b = blockIdx.x, tid = threadIdx.x;
    sp[tid]       = pooled[(size_t)b * 512 + tid];
    sp[tid + 256] = pooled[(size_t)b * 512 + 256 + tid];
    __syncthreads();
    float a1 = 0.f;
    for (int k = 0; k < 512; k++) a1 = fmaf(sp[k], Wout[(size_t)k * 256 + tid], a1);
    s1[tid] = a1;
    __syncthreads();
    if (tid < 128) {
        float a2 = bc1[tid];
        for (int k = 0; k < 256; k++) a2 = fmaf(s1[k], Wc1[(size_t)k * 128 + tid], a2);
        s2[tid] = a2;
    }
    __syncthreads();
    if (tid < 12) {
        float a3 = bc2[tid];
        for (int k = 0; k < 128; k++) a3 = fmaf(s2[k], Wc2[(size_t)k * 12 + tid], a3);
        out[(size_t)b * 12 + tid] = a3;
    }
}

// ---------------------------------------------------------------------------
extern "C" void kernel_launch(void* const* d_in, const int* in_sizes, int n_in,
                              void* d_out, int out_size, void* d_ws,
                              size_t ws_size, hipStream_t stream)
{
    const float* x      = (const float*)d_in[0];
    const float* Wproj  = (const float*)d_in[1];
    const float* bproj  = (const float*)d_in[2];
    const float* Win    = (const float*)d_in[3];
    const float* convw  = (const float*)d_in[4];
    const float* convb  = (const float*)d_in[5];
    const float* Wx     = (const float*)d_in[6];
    const float* Wdt    = (const float*)d_in[7];
    const float* bdt    = (const float*)d_in[8];
    const float* Alog   = (const float*)d_in[9];
    const float* Dparam = (const float*)d_in[10];
    const float* Wout   = (const float*)d_in[11];
    const float* Wc1    = (const float*)d_in[12];
    const float* bc1    = (const float*)d_in[13];
    const float* Wc2    = (const float*)d_in[14];
    const float* bc2    = (const float*)d_in[15];
    float* out = (float*)d_out;

    // fixed fp32 region: Wcomb 65536 + bcomb 1024 + xdbl 6291456 + pooled 65536
    const size_t fixedB = 6423552ull * 4;            // 25.69 MB
    const size_t halfB  = 67108864ull * 2;           // 134.2 MB per fp16 array
    const size_t perPB  = 3211264ull * 4;            // 12.85 MB per chunk index

    int P = 8;
    bool pathA = false;
    for (int p = 8; p >= 1; p >>= 1) {
        if (fixedB + 2 * halfB + (size_t)p * perPB <= ws_size) {
            P = p; pathA = true; break;
        }
    }
    if (!pathA) {
        P = 8;
        while (P > 1 && fixedB + (size_t)P * perPB > ws_size) P >>= 1;
    }

    char*  wsc    = (char*)d_ws;
    float* Wcomb  = (float*)wsc;
    float* bcomb  = Wcomb + 65536;
    float* xdbl   = bcomb + 1024;
    float* pooled = xdbl + 6291456;
    __half* xms   = (__half*)(wsc + fixedB);
    __half* zss   = xms + 67108864ull;
    float* chunk0 = pathA ? (float*)(wsc + fixedB + 2 * halfB)
                          : (float*)(wsc + fixedB);
    float* Pprod  = chunk0;
    float* Hloc   = Pprod + (size_t)P * 1048576;
    float* Kcoef  = Hloc  + (size_t)P * 1048576;
    float* AccLoc = Kcoef + (size_t)P * 1048576;

    fold_k<<<256, 256, 0, stream>>>(Wproj, bproj, Win, Wcomb, bcomb);

    const int Lc = LLEN / P;
    if (pathA) {
        convgemm_k<1><<<MROWS / 64, 256, 0, stream>>>(
            x, Wcomb, bcomb, Wx, convw, convb, xdbl, xms, zss);
        scanA2_k<<<dim3(DI / 256, P, BCONST), 256, 0, stream>>>(
            xms, zss, xdbl, Wdt, bdt, Alog, Dparam, Lc,
            Pprod, Hloc, Kcoef, AccLoc);
    } else {
        convgemm_k<0><<<MROWS / 64, 256, 0, stream>>>(
            x, Wcomb, bcomb, Wx, convw, convb, xdbl, nullptr, nullptr);
        scanA_k<<<dim3(DI / 256, P, BCONST), 256, 0, stream>>>(
            x, Wcomb, bcomb, xdbl, Wdt, bdt, Alog, Dparam, convw, convb, Lc,
            Pprod, Hloc, Kcoef, AccLoc);
    }
    scanB_k<<<dim3(DI / 256, BCONST), 256, 0, stream>>>(
        Pprod, Hloc, Kcoef, AccLoc, P, pooled);
    cls_k<<<BCONST, 256, 0, stream>>>(pooled, Wout, Wc1, bc1, Wc2, bc2, out);
}

// Round 7
// 1190.437 us; speedup vs baseline: 1.5979x; 1.5979x over previous
//
#include <hip/hip_runtime.h>
#include <hip/hip_bf16.h>
#include <hip/hip_fp16.h>

#define BCONST 128
#define LLEN   1024
#define INDIM  64
#define DI     512
#define MROWS  (BCONST*LLEN)
#define GRP    4
#define BG     32                 // batches per group
#define MG     (BG*LLEN)          // 32768 rows per group
#define PCH    16                 // chunks per sequence
#define LC     (LLEN/PCH)         // 64 steps per chunk

__device__ __forceinline__ float sigmoidf_(float x) {
    return __fdividef(1.0f, 1.0f + __expf(-x));
}

// ---------------------------------------------------------------------------
// fold_k: Wcomb = W_proj_in @ W_in  (64x1024); bcomb = b_proj_in @ W_in
// ---------------------------------------------------------------------------
__global__ __launch_bounds__(256) void fold_k(
    const float* __restrict__ Wp, const float* __restrict__ bp,
    const float* __restrict__ Win, float* __restrict__ Wcomb,
    float* __restrict__ bcomb)
{
    const int k = blockIdx.x >> 2;
    const int n = (blockIdx.x & 3) * 256 + threadIdx.x;
    float acc = 0.f;
    for (int j = 0; j < 256; j++)
        acc = fmaf(Wp[k * 256 + j], Win[(size_t)j * 1024 + n], acc);
    Wcomb[(size_t)k * 1024 + n] = acc;
    if (k == 0) {
        float bacc = 0.f;
        for (int j = 0; j < 256; j++)
            bacc = fmaf(bp[j], Win[(size_t)j * 1024 + n], bacc);
        bcomb[n] = bacc;
    }
}

// ---------------------------------------------------------------------------
// xz_k: per-group K=64 GEMM  xz = x@Wcomb + bcomb  (128-row x 64-col tiles)
// epilogue: d<512 -> halo-recompute + causal conv + silu -> fp16 xms
//           d>=512 -> silu -> fp16 zss
// ---------------------------------------------------------------------------
__global__ __launch_bounds__(256) void xz_k(
    const float* __restrict__ x,      // group base [MG][64]
    const float* __restrict__ Wcomb,  // [64][1024]
    const float* __restrict__ bcomb,  // [1024]
    const float* __restrict__ cw, const float* __restrict__ cb,
    __half* __restrict__ xms, __half* __restrict__ zss)
{
    __shared__ float xs[131][68];     // x rows gm0-3..gm0+127; later conv tile
    __shared__ float ws[64][64];      // Wcomb k x n-slice

    const int tid = threadIdx.x;
    const int tni = tid & 15;
    const int tmi = tid >> 4;
    const int n0  = blockIdx.x * 64;
    const int gm0 = blockIdx.y * 128;
    const bool seqstart = ((gm0 & (LLEN - 1)) == 0);

    for (int q = tid; q < 131 * 16; q += 256) {
        int i = q >> 4, c4 = (q & 15) * 4;
        float4 v = make_float4(0.f, 0.f, 0.f, 0.f);
        if (!(seqstart && i < 3))
            v = *reinterpret_cast<const float4*>(&x[(size_t)(gm0 - 3 + i) * 64 + c4]);
        *reinterpret_cast<float4*>(&xs[i][c4]) = v;
    }
    for (int q = tid; q < 64 * 16; q += 256) {
        int k = q >> 4, c4 = (q & 15) * 4;
        *reinterpret_cast<float4*>(&ws[k][c4]) =
            *reinterpret_cast<const float4*>(&Wcomb[(size_t)k * 1024 + n0 + c4]);
    }
    __syncthreads();

    float acc[8][4];
#pragma unroll
    for (int i = 0; i < 8; i++)
#pragma unroll
        for (int j = 0; j < 4; j++) acc[i][j] = 0.f;

#pragma unroll
    for (int k4 = 0; k4 < 16; k4++) {
        float4 b0 = *reinterpret_cast<const float4*>(&ws[k4 * 4 + 0][tni * 4]);
        float4 b1 = *reinterpret_cast<const float4*>(&ws[k4 * 4 + 1][tni * 4]);
        float4 b2 = *reinterpret_cast<const float4*>(&ws[k4 * 4 + 2][tni * 4]);
        float4 b3 = *reinterpret_cast<const float4*>(&ws[k4 * 4 + 3][tni * 4]);
#pragma unroll
        for (int i = 0; i < 8; i++) {
            float4 a = *reinterpret_cast<const float4*>(&xs[3 + tmi + 16 * i][k4 * 4]);
            acc[i][0] = fmaf(a.x, b0.x, fmaf(a.y, b1.x, fmaf(a.z, b2.x, fmaf(a.w, b3.x, acc[i][0]))));
            acc[i][1] = fmaf(a.x, b0.y, fmaf(a.y, b1.y, fmaf(a.z, b2.y, fmaf(a.w, b3.y, acc[i][1]))));
            acc[i][2] = fmaf(a.x, b0.z, fmaf(a.y, b1.z, fmaf(a.z, b2.z, fmaf(a.w, b3.z, acc[i][2]))));
            acc[i][3] = fmaf(a.x, b0.w, fmaf(a.y, b1.w, fmaf(a.z, b2.w, fmaf(a.w, b3.w, acc[i][3]))));
        }
    }

    const int dcol0 = n0 + tni * 4;
    float bb[4];
#pragma unroll
    for (int j = 0; j < 4; j++) bb[j] = bcomb[dcol0 + j];

    if (n0 < 512) {
        // halo rows gm0-3..gm0-1 recomputed (zeros at sequence start)
        float halo = 0.f;
        const int hr = tid >> 6, hc = tid & 63;
        if (!seqstart && tid < 192) {
            halo = bcomb[n0 + hc];
            for (int k = 0; k < 64; k++)
                halo = fmaf(xs[hr][k], ws[k][hc], halo);
        }
        __syncthreads();                   // all GEMM/halo reads of xs done
        if (tid < 192) xs[hr][hc] = halo;  // pad rows (0 at seq start)
#pragma unroll
        for (int i = 0; i < 8; i++) {
            int r = tmi + 16 * i;
#pragma unroll
            for (int j = 0; j < 4; j++) xs[3 + r][tni * 4 + j] = acc[i][j] + bb[j];
        }
        __syncthreads();

        float cwr[4][4], cbv[4];
#pragma unroll
        for (int j = 0; j < 4; j++) {
            cbv[j] = cb[dcol0 + j];
#pragma unroll
            for (int t = 0; t < 4; t++) cwr[j][t] = cw[(dcol0 + j) * 4 + t];
        }
#pragma unroll
        for (int i = 0; i < 8; i++) {
            int r = tmi + 16 * i;
            float s[4];
#pragma unroll
            for (int j = 0; j < 4; j++) {
                int cc = tni * 4 + j;
                float v = cbv[j];
                v = fmaf(xs[r + 0][cc], cwr[j][0], v);
                v = fmaf(xs[r + 1][cc], cwr[j][1], v);
                v = fmaf(xs[r + 2][cc], cwr[j][2], v);
                v = fmaf(xs[r + 3][cc], cwr[j][3], v);
                s[j] = v * sigmoidf_(v);
            }
            union { __half2 h2[2]; uint2 u; } pk;
            pk.h2[0] = __halves2half2(__float2half(s[0]), __float2half(s[1]));
            pk.h2[1] = __halves2half2(__float2half(s[2]), __float2half(s[3]));
            *reinterpret_cast<uint2*>(&xms[(size_t)(gm0 + r) * DI + dcol0]) = pk.u;
        }
    } else {
#pragma unroll
        for (int i = 0; i < 8; i++) {
            int r = tmi + 16 * i;
            float s[4];
#pragma unroll
            for (int j = 0; j < 4; j++) {
                float v = acc[i][j] + bb[j];
                s[j] = v * sigmoidf_(v);
            }
            union { __half2 h2[2]; uint2 u; } pk;
            pk.h2[0] = __halves2half2(__float2half(s[0]), __float2half(s[1]));
            pk.h2[1] = __halves2half2(__float2half(s[2]), __float2half(s[3]));
            *reinterpret_cast<uint2*>(&zss[(size_t)(gm0 + r) * DI + dcol0 - 512]) = pk.u;
        }
    }
}

// ---------------------------------------------------------------------------
// xdbl_k: xdblg = xms(fp16, MG x 512) @ Wx(512 x 48) -> fp32.  BM=32.
// ---------------------------------------------------------------------------
__global__ __launch_bounds__(256) void xdbl_k(
    const __half* __restrict__ xms, const float* __restrict__ Wx,
    float* __restrict__ xdblg)
{
    __shared__ float As[16][36];
    __shared__ float Bs[16][48];
    const int tid = threadIdx.x;
    const int tni = tid & 15;     // cols tni*3..+2
    const int tmi = tid >> 4;     // rows tmi*2..+1
    const int gm0 = blockIdx.x * 32;

    float acc[2][3];
#pragma unroll
    for (int i = 0; i < 2; i++)
#pragma unroll
        for (int j = 0; j < 3; j++) acc[i][j] = 0.f;

    for (int kt = 0; kt < DI; kt += 16) {
        __syncthreads();
        if (tid < 128) {
            int row = tid >> 2, k4 = (tid & 3) * 4;
            union { uint2 u; __half2 h2[2]; } pk;
            pk.u = *reinterpret_cast<const uint2*>(&xms[(size_t)(gm0 + row) * DI + kt + k4]);
            float2 f0 = __half22float2(pk.h2[0]);
            float2 f1 = __half22float2(pk.h2[1]);
            As[k4 + 0][row] = f0.x; As[k4 + 1][row] = f0.y;
            As[k4 + 2][row] = f1.x; As[k4 + 3][row] = f1.y;
        }
        for (int q = tid; q < 768; q += 256) {
            int kr = q / 48, nc = q - kr * 48;
            Bs[kr][nc] = Wx[(size_t)(kt + kr) * 48 + nc];
        }
        __syncthreads();
#pragma unroll
        for (int kk = 0; kk < 16; kk++) {
            float a0 = As[kk][tmi * 2 + 0];
            float a1 = As[kk][tmi * 2 + 1];
            float b0 = Bs[kk][tni * 3 + 0];
            float b1 = Bs[kk][tni * 3 + 1];
            float b2 = Bs[kk][tni * 3 + 2];
            acc[0][0] = fmaf(a0, b0, acc[0][0]);
            acc[0][1] = fmaf(a0, b1, acc[0][1]);
            acc[0][2] = fmaf(a0, b2, acc[0][2]);
            acc[1][0] = fmaf(a1, b0, acc[1][0]);
            acc[1][1] = fmaf(a1, b1, acc[1][1]);
            acc[1][2] = fmaf(a1, b2, acc[1][2]);
        }
    }
#pragma unroll
    for (int i = 0; i < 2; i++)
#pragma unroll
        for (int j = 0; j < 3; j++)
            xdblg[(size_t)(gm0 + tmi * 2 + i) * 48 + tni * 3 + j] = acc[i][j];
}

// ---------------------------------------------------------------------------
// scanA2_k: chunked scan, thread=(b,d,c). fp16 xms/zss; xdbl rows via LDS.
// Register arrays: 80 floats -> no spill.  Writes fp16 chunk coefficients.
// ---------------------------------------------------------------------------
__global__ __launch_bounds__(256, 4) void scanA2_k(
    const __half* __restrict__ xms, const __half* __restrict__ zss,
    const float* __restrict__ xdblg, const float* __restrict__ Wdt,
    const float* __restrict__ bdt_g, const float* __restrict__ Alog,
    const float* __restrict__ Dp_g,
    __half* __restrict__ Pp, __half* __restrict__ Hl,
    __half* __restrict__ Kc, float* __restrict__ AccL)
{
    __shared__ float rows[LC][48];
    const int tid = threadIdx.x;
    const int d   = blockIdx.x * 256 + tid;
    const int c   = blockIdx.y;
    const int b   = blockIdx.z;
    const int l0  = c * LC;

    for (int q = tid; q < LC * 12; q += 256) {
        int row = q / 12, c4 = (q % 12) * 4;
        *reinterpret_cast<float4*>(&rows[row][c4]) =
            *reinterpret_cast<const float4*>(
                &xdblg[(size_t)(b * LLEN + l0 + row) * 48 + c4]);
    }

    float wdt[16], Av[16], h[16], p[16], K[16];
#pragma unroll
    for (int r = 0; r < 16; r++) wdt[r] = Wdt[r * DI + d];
#pragma unroll
    for (int n = 0; n < 16; n++) Av[n] = -__expf(Alog[d * 16 + n]);
#pragma unroll
    for (int n = 0; n < 16; n++) { h[n] = 0.f; p[n] = 1.f; K[n] = 0.f; }
    const float bdt = bdt_g[d], Dpv = Dp_g[d];

    const __half* xmp = xms + ((size_t)b * LLEN + l0) * DI + d;
    const __half* zsp = zss + ((size_t)b * LLEN + l0) * DI + d;
    float acc = 0.f;
    __syncthreads();

    for (int t = 0; t < LC; t++) {
        float xv_ = __half2float(xmp[(size_t)t * DI]);
        float zs  = __half2float(zsp[(size_t)t * DI]);
        const float* rw = &rows[t][0];

        float dtp = bdt;
#pragma unroll
        for (int r4 = 0; r4 < 4; r4++) {
            float4 rv = *reinterpret_cast<const float4*>(rw + r4 * 4);
            dtp = fmaf(rv.x, wdt[r4 * 4 + 0], dtp);
            dtp = fmaf(rv.y, wdt[r4 * 4 + 1], dtp);
            dtp = fmaf(rv.z, wdt[r4 * 4 + 2], dtp);
            dtp = fmaf(rv.w, wdt[r4 * 4 + 3], dtp);
        }
        float dt = (dtp > 15.f) ? dtp : __logf(1.f + __expf(dtp));
        float dtx = dt * xv_;
        float y = 0.f;
#pragma unroll
        for (int n4 = 0; n4 < 4; n4++) {
            float4 Bv = *reinterpret_cast<const float4*>(rw + 16 + n4 * 4);
            float4 Cv = *reinterpret_cast<const float4*>(rw + 32 + n4 * 4);
            float Ba[4] = {Bv.x, Bv.y, Bv.z, Bv.w};
            float Ca[4] = {Cv.x, Cv.y, Cv.z, Cv.w};
#pragma unroll
            for (int q = 0; q < 4; q++) {
                int n = n4 * 4 + q;
                float e = __expf(dt * Av[n]);
                h[n] = fmaf(e, h[n], dtx * Ba[q]);
                p[n] *= e;
                y = fmaf(h[n], Ca[q], y);
                K[n] = fmaf(p[n], Ca[q] * zs, K[n]);
            }
        }
        acc = fmaf(y + xv_ * Dpv, zs, acc);
    }

    const size_t nbase = ((size_t)(b * PCH + c) * 16) * DI + d;
#pragma unroll
    for (int n = 0; n < 16; n++) {
        Pp[nbase + (size_t)n * DI] = __float2half(p[n]);
        Hl[nbase + (size_t)n * DI] = __float2half(h[n]);
        Kc[nbase + (size_t)n * DI] = __float2half(K[n]);
    }
    AccL[(size_t)(b * PCH + c) * DI + d] = acc;
}

// ---------------------------------------------------------------------------
// scanB_k: chain PCH chunks per (b,d); emit pooled for this group.
// ---------------------------------------------------------------------------
__global__ __launch_bounds__(256) void scanB_k(
    const __half* __restrict__ Pp, const __half* __restrict__ Hl,
    const __half* __restrict__ Kc, const float* __restrict__ AccL,
    int gb0, float* __restrict__ pooled)
{
    const int tid = threadIdx.x;
    const int d   = blockIdx.x * 256 + tid;
    const int b   = blockIdx.y;
    float h[16];
#pragma unroll
    for (int n = 0; n < 16; n++) h[n] = 0.f;
    float acc = 0.f;
    for (int c = 0; c < PCH; c++) {
        const size_t nbase = ((size_t)(b * PCH + c) * 16) * DI + d;
        acc += AccL[(size_t)(b * PCH + c) * DI + d];
#pragma unroll
        for (int n = 0; n < 16; n++)
            acc = fmaf(__half2float(Kc[nbase + (size_t)n * DI]), h[n], acc);
#pragma unroll
        for (int n = 0; n < 16; n++)
            h[n] = fmaf(__half2float(Pp[nbase + (size_t)n * DI]), h[n],
                        __half2float(Hl[nbase + (size_t)n * DI]));
    }
    pooled[(size_t)(gb0 + b) * DI + d] = acc * (1.0f / LLEN);
}

// ---------------------------------------------------------------------------
__global__ __launch_bounds__(256) void cls_k(
    const float* __restrict__ pooled, const float* __restrict__ Wout,
    const float* __restrict__ Wc1, const float* __restrict__ bc1,
    const float* __restrict__ Wc2, const float* __restrict__ bc2,
    float* __restrict__ out)
{
    __shared__ float sp[512];
    __shared__ float s1[256];
    __shared__ float s2[128];
    const int b = blockIdx.x, tid = threadIdx.x;
    sp[tid]       = pooled[(size_t)b * 512 + tid];
    sp[tid + 256] = pooled[(size_t)b * 512 + 256 + tid];
    __syncthreads();
    float a1 = 0.f;
    for (int k = 0; k < 512; k++) a1 = fmaf(sp[k], Wout[(size_t)k * 256 + tid], a1);
    s1[tid] = a1;
    __syncthreads();
    if (tid < 128) {
        float a2 = bc1[tid];
        for (int k = 0; k < 256; k++) a2 = fmaf(s1[k], Wc1[(size_t)k * 128 + tid], a2);
        s2[tid] = a2;
    }
    __syncthreads();
    if (tid < 12) {
        float a3 = bc2[tid];
        for (int k = 0; k < 128; k++) a3 = fmaf(s2[k], Wc2[(size_t)k * 12 + tid], a3);
        out[(size_t)b * 12 + tid] = a3;
    }
}

// ---------------------------------------------------------------------------
extern "C" void kernel_launch(void* const* d_in, const int* in_sizes, int n_in,
                              void* d_out, int out_size, void* d_ws,
                              size_t ws_size, hipStream_t stream)
{
    const float* x      = (const float*)d_in[0];
    const float* Wproj  = (const float*)d_in[1];
    const float* bproj  = (const float*)d_in[2];
    const float* Win    = (const float*)d_in[3];
    const float* convw  = (const float*)d_in[4];
    const float* convb  = (const float*)d_in[5];
    const float* Wx     = (const float*)d_in[6];
    const float* Wdt    = (const float*)d_in[7];
    const float* bdt    = (const float*)d_in[8];
    const float* Alog   = (const float*)d_in[9];
    const float* Dparam = (const float*)d_in[10];
    const float* Wout   = (const float*)d_in[11];
    const float* Wc1    = (const float*)d_in[12];
    const float* bc1    = (const float*)d_in[13];
    const float* Wc2    = (const float*)d_in[14];
    const float* bc2    = (const float*)d_in[15];
    float* out = (float*)d_out;

    // workspace layout (total ~100.4 MB, < 128.5 MB known-safe)
    char* wsc = (char*)d_ws;
    float*  Wcomb  = (float*)wsc;                       // 65536 f
    float*  bcomb  = Wcomb + 65536;                     // 1024 f
    float*  pooled = bcomb + 1024;                      // 65536 f
    float*  xdblg  = pooled + 65536;                    // MG*48 f  (6.29 MB)
    __half* xms    = (__half*)(xdblg + (size_t)MG * 48);        // MG*512 h
    __half* zss    = xms + (size_t)MG * DI;                     // MG*512 h
    __half* Pp     = zss + (size_t)MG * DI;                     // BG*PCH*16*DI h
    __half* Hl     = Pp + (size_t)BG * PCH * 16 * DI;
    __half* Kc     = Hl + (size_t)BG * PCH * 16 * DI;
    float*  AccL   = (float*)(Kc + (size_t)BG * PCH * 16 * DI); // BG*PCH*DI f

    fold_k<<<256, 256, 0, stream>>>(Wproj, bproj, Win, Wcomb, bcomb);

    for (int g = 0; g < GRP; g++) {
        const float* xg = x + (size_t)g * MG * INDIM;
        xz_k<<<dim3(16, MG / 128), 256, 0, stream>>>(
            xg, Wcomb, bcomb, convw, convb, xms, zss);
        xdbl_k<<<MG / 32, 256, 0, stream>>>(xms, Wx, xdblg);
        scanA2_k<<<dim3(2, PCH, BG), 256, 0, stream>>>(
            xms, zss, xdblg, Wdt, bdt, Alog, Dparam, Pp, Hl, Kc, AccL);
        scanB_k<<<dim3(2, BG), 256, 0, stream>>>(
            Pp, Hl, Kc, AccL, g * BG, pooled);
    }
    cls_k<<<BCONST, 256, 0, stream>>>(pooled, Wout, Wc1, bc1, Wc2, bc2, out);
}